// Round 4
// baseline (359.243 us; speedup 1.0000x reference)
//
#include <hip/hip_runtime.h>

// Problem constants (static in the reference)
#define NN 1024
#define MM 64
#define BB 8
#define EE 63456   // sum_i min(i,64) = 2016 + 960*64

// ws float layout
#define WS_WNd   0        // Wn_eff dst rows: [64 c][64 n] fp32 (for rank-1 hoist)
#define WS_BN    4096     // bn_eff 64 fp32
#define WS_BE    4160     // be_eff 64 fp32
#define WS_B2H   4224     // B2 hi: [4 nt][8 ks][64 lane][8 e] ushort = 16384 us
#define WS_B2L   12416    // B2 lo
#define WS_B5H   20608    // B5 hi: [2 nt][8 ks][64 lane][8 e] ushort = 8192 us
#define WS_B5L   24704    // B5 lo
#define WS_TOTAL 28800    // floats (~115 KB)

using short8 = __attribute__((ext_vector_type(8))) short;
using f32x16 = __attribute__((ext_vector_type(16))) float;

__device__ __forceinline__ unsigned bf16_rne(float x) {
    unsigned u = __float_as_uint(x);
    return (u + 0x7fffu + ((u >> 16) & 1u)) >> 16;
}

// Single prep kernel: collapse inner linear pairs (no inner ReLU in the ref!)
// and pack split-bf16 B fragments directly. All outputs independent.
// B-fragment (32x32x16): lane l holds n = nt*32+(l&31), k = ks*16+(l>>5)*8+e.
// B2 (K=128: [src;edge], N=128: [accn | acce]); B5 = Wef (K=128, N=64).
__global__ void prep_kernel(
    const float* __restrict__ Wn1, const float* __restrict__ bn1,
    const float* __restrict__ Wn2, const float* __restrict__ bn2,
    const float* __restrict__ We1, const float* __restrict__ be1,
    const float* __restrict__ We2, const float* __restrict__ be2,
    const float* __restrict__ Wef, float* __restrict__ ws)
{
    int idx = blockIdx.x * 256 + threadIdx.x;
    if (idx < 16384) {                      // B2 fragments (needs collapse dot)
        int e = idx & 7, l = (idx >> 3) & 63, ks = (idx >> 9) & 7, nt = idx >> 12;
        int k = ks * 16 + (l >> 5) * 8 + e;
        int n = nt * 32 + (l & 31);
        float acc = 0.f;
        if (n < 64) {                       // Wn_eff: rows [src 0..63 | dst 64..127 | edge 128..191]
            int r = (k < 64) ? k : (64 + k);
            for (int t = 0; t < 128; ++t) acc += Wn1[r * 128 + t] * Wn2[t * 64 + n];
        } else {                            // We_eff: rows [src 0..63 | edge 64..127]
            for (int t = 0; t < 128; ++t) acc += We1[k * 128 + t] * We2[t * 64 + (n - 64)];
        }
        unsigned hh = bf16_rne(acc);
        unsigned ll = bf16_rne(acc - __uint_as_float(hh << 16));
        ((unsigned short*)(ws + WS_B2H))[idx] = (unsigned short)hh;
        ((unsigned short*)(ws + WS_B2L))[idx] = (unsigned short)ll;
    } else if (idx < 24576) {               // B5 fragments (direct from Wef)
        int t2 = idx - 16384;
        int e = t2 & 7, l = (t2 >> 3) & 63, ks = (t2 >> 9) & 7, nt = t2 >> 12;
        int k = ks * 16 + (l >> 5) * 8 + e;
        int n = nt * 32 + (l & 31);
        float v = Wef[k * 64 + n];
        unsigned hh = bf16_rne(v);
        unsigned ll = bf16_rne(v - __uint_as_float(hh << 16));
        ((unsigned short*)(ws + WS_B5H))[t2] = (unsigned short)hh;
        ((unsigned short*)(ws + WS_B5L))[t2] = (unsigned short)ll;
    } else if (idx < 28672) {               // Wn_eff dst rows, fp32 (rank-1 hoist)
        int t2 = idx - 24576; int c = t2 >> 6, n = t2 & 63;
        float acc = 0.f;
        for (int q = 0; q < 128; ++q) acc += Wn1[(64 + c) * 128 + q] * Wn2[q * 64 + n];
        ws[WS_WNd + t2] = acc;              // layout [c][n]
    } else if (idx < 28800) {               // biases
        int t2 = idx - 28672;
        if (t2 < 64) {
            float a = bn2[t2];
            for (int q = 0; q < 128; ++q) a += bn1[q] * Wn2[q * 64 + t2];
            ws[WS_BN + t2] = a;
        } else {
            int n = t2 - 64;
            float a = be2[n];
            for (int q = 0; q < 128; ++q) a += be1[q] * We2[q * 64 + n];
            ws[WS_BE + n] = a;
        }
    }
}

// Main kernel: one block of 512 threads (8 waves) per (b, i).
// A (64 rows x 128 ch [src||edge]) staged hi-bf16 only in LDS (16 KB),
// 16B-unit XOR swizzle (u ^ (row&15)). B split-bf16 from ws: 2 MFMA/k-step.
// Phase2: 8 waves = 4 N-slabs x 2 M-tiles, 16 MFMA each (one 32x32 C tile).
// pair_e = relu bf16 overwrites A's src half. Phase5: waves 0-3 compute zz
// (pair@Wef[:64]) + prefix scan; waves 4-7 compute ze (edge@Wef[64:]) and
// exchange it through the freed s_A (fp32), plus the out_nodes GEMV.
__global__ __launch_bounds__(512, 8)
void main_kernel(const float* __restrict__ nodes,
                 const float* __restrict__ edges,
                 const float* __restrict__ ws,
                 const float* __restrict__ Wnf,   // W_nodes (128x64) fp32
                 const float* __restrict__ bias,  // bias_edges (64) — both outputs use it (ref quirk)
                 float* __restrict__ out)
{
    __shared__ __align__(16) unsigned short s_A[64 * 128];  // 16 KB; later ze overlay f32[64*64]
    __shared__ float s_red[3 * 64];  // rows 0,1: accn partials (by mt); row 2: scan totals
    __shared__ float s_dd[64];
    __shared__ float s_dst[64];
    __shared__ float s_gn[4 * 64];

    const int tid = threadIdx.x;
    const int bx  = blockIdx.x;
    const int b   = bx >> 10;
    const int i   = bx & 1023;
    const int w   = (i < MM) ? i : MM;
    const long ns_ = (i <= 64) ? ((long)i * (i - 1)) / 2 : 2016L + (long)(i - 64) * 64;

    // ---- stage dst row (fp32) + A as hi-bf16, swizzled ----
    if (tid < 16)
        *(float4*)&s_dst[tid * 4] = ((const float4*)(nodes + ((size_t)b * NN + i) * 64))[tid];
    for (int idx = tid; idx < w * 16; idx += 512) {
        const int row = idx >> 4, q = idx & 15;   // q<8: src unit ; q>=8: edge unit
        const float* src = (q < 8)
            ? (nodes + ((size_t)b * NN + (i - w) + row) * 64 + q * 8)
            : (edges + ((size_t)b * EE + ns_ + row) * 64 + (q - 8) * 8);
        float4 x0 = *(const float4*)src;
        float4 x1 = *(const float4*)(src + 4);
        unsigned h0 = bf16_rne(x0.x), h1 = bf16_rne(x0.y), h2 = bf16_rne(x0.z), h3 = bf16_rne(x0.w);
        unsigned h4 = bf16_rne(x1.x), h5 = bf16_rne(x1.y), h6 = bf16_rne(x1.z), h7 = bf16_rne(x1.w);
        uint4 H;
        H.x = h0 | (h1 << 16); H.y = h2 | (h3 << 16);
        H.z = h4 | (h5 << 16); H.w = h6 | (h7 << 16);
        *(uint4*)&s_A[row * 128 + (q ^ (row & 15)) * 8] = H;
    }
    __syncthreads();                                      // B1

    const int wv = tid >> 6, l = tid & 63, lo5 = l & 31, hi = l >> 5;
    const int mt = wv & 1;                                 // M-tile (rows mt*32..)

    // ---- wave 0: ddn[f] = bn_eff[f] + dst . Wn_eff_dst[.][f] (read after B2) ----
    if (wv == 0) {
        const float* wsd = ws + WS_WNd;
        float acc = ws[WS_BN + l];
        for (int c = 0; c < 64; ++c) acc += s_dst[c] * wsd[c * 64 + l];
        s_dd[l] = acc;
    }

    // ---- Phase 2: one 32x32 C tile per wave: slab = wv>>1 (N), mt (M) ----
    f32x16 acc = {};
    {
        const int slab = wv >> 1;
        const unsigned short* Bh = (const unsigned short*)(ws + WS_B2H);
        const unsigned short* Bl = (const unsigned short*)(ws + WS_B2L);
        const int r = mt * 32 + lo5;
#pragma unroll
        for (int ks = 0; ks < 8; ++ks) {
            short8 bh = *(const short8*)&Bh[((slab * 8 + ks) * 64 + l) * 8];
            short8 bl = *(const short8*)&Bl[((slab * 8 + ks) * 64 + l) * 8];
            const int u = ks * 2 + hi;
            short8 a = *(const short8*)&s_A[r * 128 + (u ^ (r & 15)) * 8];
            acc = __builtin_amdgcn_mfma_f32_32x32x16_bf16(a, bh, acc, 0, 0, 0);
            acc = __builtin_amdgcn_mfma_f32_32x32x16_bf16(a, bl, acc, 0, 0, 0);
        }
    }
    __syncthreads();                                      // B2 (all A reads done)

    if (wv < 4) {
        // accn: per-column partial sums of relu(C + dd) over this wave's 32 rows
        const int f = (wv >> 1) * 32 + lo5;
        const float dd = s_dd[f];
        float sum = 0.f;
#pragma unroll
        for (int reg = 0; reg < 16; ++reg) {
            const int r = mt * 32 + (reg & 3) + 8 * (reg >> 2) + 4 * hi;
            if (r < w) sum += fmaxf(acc[reg] + dd, 0.f);
        }
        sum += __shfl_xor(sum, 32);
        if (hi == 0) s_red[mt * 64 + f] = sum;
    } else {
        // acce: pair_e = relu(C + be) -> bf16 -> overwrite A src half (k = fp)
        const int fp = ((wv >> 1) - 2) * 32 + lo5;
        const float be = ws[WS_BE + fp];
        const int uoff = fp >> 3, foff = fp & 7;
#pragma unroll
        for (int reg = 0; reg < 16; ++reg) {
            const int j = mt * 32 + (reg & 3) + 8 * (reg >> 2) + 4 * hi;
            float p = (j < w) ? fmaxf(acc[reg] + be, 0.f) : 0.f;
            s_A[j * 128 + (uoff ^ (j & 15)) * 8 + foff] = (unsigned short)bf16_rne(p);
        }
    }
    __syncthreads();                                      // B3 (pair in LDS; s_red ready)

    // ---- Phase 5: wv0-3 (dup=0): zz = pair@Wef[0:64]; wv4-7 (dup=1): ze = edge@Wef[64:128] ----
    float* s_ze = (float*)s_A;
    const int ntc = (wv >> 1) & 1;
    const int dup = wv >> 2;
    const int rbase = mt * 32;
    f32x16 z = {};
    {
        const unsigned short* Bh = (const unsigned short*)(ws + WS_B5H);
        const unsigned short* Bl = (const unsigned short*)(ws + WS_B5L);
        const int r = rbase + lo5;
        const int k0 = dup ? 4 : 0;
#pragma unroll
        for (int kk = 0; kk < 4; ++kk) {
            const int ks = k0 + kk;
            short8 bh = *(const short8*)&Bh[((ntc * 8 + ks) * 64 + l) * 8];
            short8 bl = *(const short8*)&Bl[((ntc * 8 + ks) * 64 + l) * 8];
            const int u = ks * 2 + hi;
            short8 a = *(const short8*)&s_A[r * 128 + (u ^ (r & 15)) * 8];
            z = __builtin_amdgcn_mfma_f32_32x32x16_bf16(a, bh, z, 0, 0, 0);
            z = __builtin_amdgcn_mfma_f32_32x32x16_bf16(a, bl, z, 0, 0, 0);
        }
    }

    float pz[16], base[4], cbase = 0.f;
    if (!dup) {
        // exclusive prefix of zz over this tile's 32 rows (in-lane + hi exchange)
        float G[4];
#pragma unroll
        for (int g = 0; g < 4; ++g) {
            float a0 = z[g * 4 + 0], a1 = z[g * 4 + 1], a2 = z[g * 4 + 2], a3 = z[g * 4 + 3];
            pz[g * 4 + 0] = 0.f;
            pz[g * 4 + 1] = a0;
            pz[g * 4 + 2] = a0 + a1;
            pz[g * 4 + 3] = a0 + a1 + a2;
            G[g] = a0 + a1 + a2 + a3;
        }
        float Gp[4];
#pragma unroll
        for (int g = 0; g < 4; ++g) Gp[g] = __shfl_xor(G[g], 32);
        float run = 0.f;
#pragma unroll
        for (int g = 0; g < 4; ++g) {
            const float g0 = hi ? Gp[g] : G[g];       // hi=0 group sum
            base[g] = run + (hi ? g0 : 0.f);
            run += G[g] + Gp[g];
        }
        if (mt == 0 && hi == 0) s_red[128 + ntc * 32 + lo5] = run;   // tile-0 column totals
    } else {
        // out_nodes GEMV partials (s_red rows 0,1 valid since B3)
        const int q = tid - 256, f = q & 63, p = q >> 6;
        const float invw = 1.0f / (float)((w > 0) ? w : 1);
        float s = 0.f;
        for (int c = p * 16; c < p * 16 + 16; ++c) {
            const float aggc = (s_red[c] + s_red[64 + c]) * invw;
            s += aggc * Wnf[c * 64 + f] + s_dst[c] * Wnf[(64 + c) * 64 + f];
        }
        s_gn[p * 64 + f] = s;
    }
    __syncthreads();                                      // B4 (all s_A reads done)

    if (dup) {
        // publish ze through freed s_A as fp32 [j][f]
#pragma unroll
        for (int reg = 0; reg < 16; ++reg) {
            const int j = rbase + (reg & 3) + 8 * (reg >> 2) + 4 * hi;
            s_ze[j * 64 + ntc * 32 + lo5] = z[reg];
        }
    }
    __syncthreads();                                      // B5

    if (!dup) {
        if (mt == 1) cbase = s_red[128 + ntc * 32 + lo5];
        const int f = ntc * 32 + lo5;
        const float bv = bias[f];
        float* oute = out + (size_t)BB * NN * 64;         // out_nodes first, then out_edges
#pragma unroll
        for (int reg = 0; reg < 16; ++reg) {
            const int j = rbase + (reg & 3) + 8 * (reg >> 2) + 4 * hi;
            if (j < w) {
                const float invj = (j > 0) ? (1.0f / (float)j) : 1.0f;
                const float zev = s_ze[j * 64 + f];
                oute[((size_t)b * EE + ns_ + j) * 64 + f] =
                    fmaxf((cbase + base[reg >> 2] + pz[reg]) * invj + zev + bv, 0.f);
            }
        }
    } else if (wv == 4 && l < 64) {
        // out_nodes combine (s_gn written pre-B4)
        const float a2 = bias[l] + s_gn[l] + s_gn[64 + l] + s_gn[128 + l] + s_gn[192 + l];
        out[((size_t)b * NN + i) * 64 + l] = fmaxf(a2, 0.f);
    }
}

extern "C" void kernel_launch(void* const* d_in, const int* in_sizes, int n_in,
                              void* d_out, int out_size, void* d_ws, size_t ws_size,
                              hipStream_t stream) {
    const float* nodes = (const float*)d_in[0];
    const float* edges = (const float*)d_in[1];
    const float* Wn1  = (const float*)d_in[2];
    const float* bn1  = (const float*)d_in[3];
    const float* Wn2  = (const float*)d_in[4];
    const float* bn2  = (const float*)d_in[5];
    const float* We1  = (const float*)d_in[6];
    const float* be1  = (const float*)d_in[7];
    const float* We2  = (const float*)d_in[8];
    const float* be2  = (const float*)d_in[9];
    const float* Wnod = (const float*)d_in[10];
    const float* Wedg = (const float*)d_in[11];
    const float* bias = (const float*)d_in[12];
    float* ws = (float*)d_ws;
    float* out = (float*)d_out;

    hipLaunchKernelGGL(prep_kernel, dim3((28800 + 255) / 256), dim3(256), 0, stream,
                       Wn1, bn1, Wn2, bn2, We1, be1, We2, be2, Wedg, ws);
    hipLaunchKernelGGL(main_kernel, dim3(BB * NN), dim3(512), 0, stream,
                       nodes, edges, ws, Wnod, bias, out);
}